// Round 1
// baseline (14810.178 us; speedup 1.0000x reference)
//
#include <hip/hip_runtime.h>
#include <hip/hip_bf16.h>
#include <math.h>

#define Bv   2
#define Sv   4096
#define Dv   768
#define Hv   12
#define DHv  64
#define BLKv 64
#define NBv  64
#define FFv  3072
#define Lv   4
#define NEGV (-1000000000.0f)

// ---------------- reductions ----------------
__device__ __forceinline__ float waveSum(float v){
#pragma unroll
  for (int o=32;o>0;o>>=1) v += __shfl_xor(v, o, 64);
  return v;
}
__device__ __forceinline__ float waveMax(float v){
#pragma unroll
  for (int o=32;o>0;o>>=1) v = fmaxf(v, __shfl_xor(v, o, 64));
  return v;
}
// blockDim must be 256 for these
__device__ __forceinline__ float blockSum256(float v){
  __shared__ float sbS[4];
  int tid = threadIdx.x;
  v = waveSum(v);
  if ((tid&63)==0) sbS[tid>>6] = v;
  __syncthreads();
  float r = sbS[0]+sbS[1]+sbS[2]+sbS[3];
  __syncthreads();
  return r;
}
__device__ __forceinline__ float blockMax256(float v){
  __shared__ float sbM[4];
  int tid = threadIdx.x;
  v = waveMax(v);
  if ((tid&63)==0) sbM[tid>>6] = v;
  __syncthreads();
  float r = fmaxf(fmaxf(sbM[0],sbM[1]), fmaxf(sbM[2],sbM[3]));
  __syncthreads();
  return r;
}

__device__ __forceinline__ float gelu_f(float x){
  return 0.5f*x*(1.0f + tanhf(0.7978845608f*(x + 0.044715f*x*x*x)));
}

// ---------------- embedding + LN ----------------
__global__ __launch_bounds__(256) void k_embed_ln(const int* __restrict__ ids,
    const float* __restrict__ wemb, const float* __restrict__ pemb,
    const float* __restrict__ gam, const float* __restrict__ bet, float* __restrict__ X)
{
  int row = blockIdx.x;
  int s = row & (Sv-1);
  int tid = threadIdx.x;
  int id = ids[row];
  float v[3];
#pragma unroll
  for (int j=0;j<3;++j){
    int c = tid + j*256;
    v[j] = wemb[(size_t)id*Dv + c] + pemb[(size_t)s*Dv + c];
  }
  float mean = blockSum256(v[0]+v[1]+v[2]) * (1.0f/Dv);
  float var = 0.f;
#pragma unroll
  for (int j=0;j<3;++j){ float t = v[j]-mean; var += t*t; }
  var = blockSum256(var) * (1.0f/Dv);
  float rs = rsqrtf(var + 1e-12f);
  float* xp = X + (size_t)row*Dv;
#pragma unroll
  for (int j=0;j<3;++j){
    int c = tid + j*256;
    xp[c] = (v[j]-mean)*rs*gam[c] + bet[c];
  }
}

// ---------------- LN (+optional residual) ----------------
__global__ __launch_bounds__(256) void k_ln(const float* __restrict__ xin, const float* __restrict__ res,
    int has_res, const float* __restrict__ gam, const float* __restrict__ bet, float* __restrict__ out)
{
  int row = blockIdx.x;
  int tid = threadIdx.x;
  float v[3];
#pragma unroll
  for (int j=0;j<3;++j){
    int c = tid + j*256;
    float t = xin[(size_t)row*Dv + c];
    if (has_res) t += res[(size_t)row*Dv + c];
    v[j] = t;
  }
  float mean = blockSum256(v[0]+v[1]+v[2]) * (1.0f/Dv);
  float var = 0.f;
#pragma unroll
  for (int j=0;j<3;++j){ float t = v[j]-mean; var += t*t; }
  var = blockSum256(var) * (1.0f/Dv);
  float rs = rsqrtf(var + 1e-12f);
  float* op = out + (size_t)row*Dv;
#pragma unroll
  for (int j=0;j<3;++j){
    int c = tid + j*256;
    op[c] = (v[j]-mean)*rs*gam[c] + bet[c];
  }
}

// ---------------- fp32 GEMM: C = A(MxK) @ Wt(KxN) + bias, optional GELU ----------------
// BM=BN=128, BK=16, 256 threads, 8x8 micro-tile split as (4+4)x(4+4) at +0/+64
__global__ __launch_bounds__(256) void k_gemm(const float* __restrict__ A, const float* __restrict__ Wt,
    const float* __restrict__ bias, float* __restrict__ C, int M, int N, int K, int act)
{
  __shared__ __align__(16) float As[16][132];
  __shared__ __align__(16) float Bs[16][132];
  int tid = threadIdx.x;
  int tx = tid & 15, ty = tid >> 4;
  int bm = blockIdx.y << 7, bn = blockIdx.x << 7;
  float acc[8][8];
#pragma unroll
  for (int u=0;u<8;++u)
#pragma unroll
    for (int v2=0;v2<8;++v2) acc[u][v2]=0.f;

  for (int k0=0;k0<K;k0+=16){
#pragma unroll
    for (int j=0;j<8;++j){
      int idx = tid + j*256;
      int mm = idx >> 4, kk = idx & 15;
      As[kk][mm] = A[(size_t)(bm+mm)*K + (k0+kk)];
      int rr = idx >> 7, cc = idx & 127;
      Bs[rr][cc] = Wt[(size_t)(k0+rr)*N + (bn+cc)];
    }
    __syncthreads();
#pragma unroll
    for (int kk=0;kk<16;++kk){
      float4 aA = *(const float4*)(&As[kk][ty*4]);
      float4 aB = *(const float4*)(&As[kk][64+ty*4]);
      float4 bA = *(const float4*)(&Bs[kk][tx*4]);
      float4 bB = *(const float4*)(&Bs[kk][64+tx*4]);
      float av[8]  = {aA.x,aA.y,aA.z,aA.w, aB.x,aB.y,aB.z,aB.w};
      float bv2[8] = {bA.x,bA.y,bA.z,bA.w, bB.x,bB.y,bB.z,bB.w};
#pragma unroll
      for (int u=0;u<8;++u)
#pragma unroll
        for (int v2=0;v2<8;++v2) acc[u][v2] += av[u]*bv2[v2];
    }
    __syncthreads();
  }

#pragma unroll
  for (int u=0;u<8;++u){
    int m = bm + ((u<4)? (ty*4+u) : (64+ty*4+(u-4)));
#pragma unroll
    for (int half=0; half<2; ++half){
      int n0 = bn + (half? (64+tx*4) : (tx*4));
      float4 r;
      r.x = acc[u][half*4+0] + bias[n0+0];
      r.y = acc[u][half*4+1] + bias[n0+1];
      r.z = acc[u][half*4+2] + bias[n0+2];
      r.w = acc[u][half*4+3] + bias[n0+3];
      if (act){ r.x=gelu_f(r.x); r.y=gelu_f(r.y); r.z=gelu_f(r.z); r.w=gelu_f(r.w); }
      *(float4*)(&C[(size_t)m*N + n0]) = r;
    }
  }
}

// ---------------- sparse attention (blocks 1..NB-2), one wave per (b,h,i), lane=q-row ----------------
__global__ __launch_bounds__(64,1) void k_attn_sparse(const float* __restrict__ Q, const float* __restrict__ K,
    const float* __restrict__ V, const int* __restrict__ amask, const int* __restrict__ rnd,
    float* __restrict__ out)
{
  int i = blockIdx.x + 1;
  int h = blockIdx.y, b = blockIdx.z;
  int tid = threadIdx.x;
  __shared__ __align__(16) float Ks[64][68];
  __shared__ __align__(16) float Vs[64][68];
  __shared__ int Ms[64];
  __shared__ int KBs[8];

  int kvs[8];
  kvs[0]=0; kvs[1]=(i>0? i-1:0); kvs[2]=i; kvs[3]=(i+1<NBv? i+1:NBv-1); kvs[4]=NBv-1;
  kvs[5]=rnd[i*3+0]; kvs[6]=rnd[i*3+1]; kvs[7]=rnd[i*3+2];
  int dupmask = 0;
#pragma unroll
  for (int a2=1;a2<8;++a2){
    bool d2=false;
#pragma unroll
    for (int b2=0;b2<a2;++b2) d2 = d2 || (kvs[a2]==kvs[b2]);
    if (d2) dupmask |= (1<<a2);
  }
  if (tid==0){
#pragma unroll
    for (int w=0;w<8;++w) KBs[w]=kvs[w];
  }

  const float* qp = Q + ((size_t)(b*Sv + i*BLKv + tid))*Dv + h*DHv;
  float qreg[64];
#pragma unroll
  for (int j=0;j<16;++j){
    float4 t = *(const float4*)(qp + 4*j);
    qreg[4*j]=t.x; qreg[4*j+1]=t.y; qreg[4*j+2]=t.z; qreg[4*j+3]=t.w;
  }
  float acc[64];
#pragma unroll
  for (int d=0; d<64; ++d) acc[d]=0.f;
  float m = -1e30f, l = 0.f;

#pragma unroll 1
  for (int w=0; w<8; ++w){
    __syncthreads();
    int kblk = KBs[w];
    const float* kp = K + ((size_t)(b*Sv + kblk*BLKv + tid))*Dv + h*DHv;
    const float* vp = V + ((size_t)(b*Sv + kblk*BLKv + tid))*Dv + h*DHv;
#pragma unroll
    for (int j=0;j<16;++j){
      *(float4*)(&Ks[tid][4*j]) = *(const float4*)(kp + 4*j);
      *(float4*)(&Vs[tid][4*j]) = *(const float4*)(vp + 4*j);
    }
    Ms[tid] = amask[b*Sv + kblk*BLKv + tid];
    __syncthreads();
    float wbias = ((dupmask>>w)&1) ? NEGV : 0.f;
#pragma unroll 1
    for (int kt=0; kt<8; ++kt){
      float sc[8];
#pragma unroll
      for (int kk=0;kk<8;++kk){
        int k = kt*8+kk;
        float s=0.f;
#pragma unroll
        for (int j=0;j<16;++j){
          float4 kvv = *(const float4*)(&Ks[k][4*j]);
          s += qreg[4*j]*kvv.x + qreg[4*j+1]*kvv.y + qreg[4*j+2]*kvv.z + qreg[4*j+3]*kvv.w;
        }
        sc[kk] = s*0.125f + wbias + (Ms[k] ? 0.f : NEGV);
      }
      float tm = m;
#pragma unroll
      for (int kk=0;kk<8;++kk) tm = fmaxf(tm, sc[kk]);
      float alpha = __expf(m - tm);
      l *= alpha;
#pragma unroll
      for (int d=0; d<64; ++d) acc[d] *= alpha;
#pragma unroll
      for (int kk=0;kk<8;++kk){
        int k = kt*8+kk;
        float p = __expf(sc[kk]-tm);
        l += p;
#pragma unroll
        for (int j=0;j<16;++j){
          float4 vv = *(const float4*)(&Vs[k][4*j]);
          acc[4*j]   += p*vv.x;
          acc[4*j+1] += p*vv.y;
          acc[4*j+2] += p*vv.z;
          acc[4*j+3] += p*vv.w;
        }
      }
      m = tm;
    }
  }
  float inv = 1.0f/l;
  float* op = out + ((size_t)(b*Sv + i*BLKv + tid))*Dv + h*DHv;
#pragma unroll
  for (int j=0;j<16;++j){
    float4 r; r.x=acc[4*j]*inv; r.y=acc[4*j+1]*inv; r.z=acc[4*j+2]*inv; r.w=acc[4*j+3]*inv;
    *(float4*)(op + 4*j) = r;
  }
}

// ---------------- global attention partials: grid.x = chunk*2+g, 8 chunks of 512 keys ----------------
__global__ __launch_bounds__(64,1) void k_attn_global(const float* __restrict__ Q, const float* __restrict__ K,
    const float* __restrict__ V, const int* __restrict__ amask,
    float* __restrict__ Pm, float* __restrict__ Pl, float* __restrict__ Pacc)
{
  int g = blockIdx.x & 1, chunk = blockIdx.x >> 1;
  int h = blockIdx.y, b = blockIdx.z;
  int tid = threadIdx.x;
  __shared__ __align__(16) float Ks[64][68];
  __shared__ __align__(16) float Vs[64][68];
  __shared__ int Ms[64];

  int qblk = g ? (NBv-1) : 0;
  const float* qp = Q + ((size_t)(b*Sv + qblk*BLKv + tid))*Dv + h*DHv;
  float qreg[64];
#pragma unroll
  for (int j=0;j<16;++j){
    float4 t = *(const float4*)(qp + 4*j);
    qreg[4*j]=t.x; qreg[4*j+1]=t.y; qreg[4*j+2]=t.z; qreg[4*j+3]=t.w;
  }
  float acc[64];
#pragma unroll
  for (int d=0; d<64; ++d) acc[d]=0.f;
  float m = -1e30f, l = 0.f;

#pragma unroll 1
  for (int w=0; w<8; ++w){
    __syncthreads();
    int kblk = chunk*8 + w;
    const float* kp = K + ((size_t)(b*Sv + kblk*BLKv + tid))*Dv + h*DHv;
    const float* vp = V + ((size_t)(b*Sv + kblk*BLKv + tid))*Dv + h*DHv;
#pragma unroll
    for (int j=0;j<16;++j){
      *(float4*)(&Ks[tid][4*j]) = *(const float4*)(kp + 4*j);
      *(float4*)(&Vs[tid][4*j]) = *(const float4*)(vp + 4*j);
    }
    Ms[tid] = amask[b*Sv + kblk*BLKv + tid];
    __syncthreads();
#pragma unroll 1
    for (int kt=0; kt<8; ++kt){
      float sc[8];
#pragma unroll
      for (int kk=0;kk<8;++kk){
        int k = kt*8+kk;
        float s=0.f;
#pragma unroll
        for (int j=0;j<16;++j){
          float4 kvv = *(const float4*)(&Ks[k][4*j]);
          s += qreg[4*j]*kvv.x + qreg[4*j+1]*kvv.y + qreg[4*j+2]*kvv.z + qreg[4*j+3]*kvv.w;
        }
        sc[kk] = s*0.125f + (Ms[k] ? 0.f : NEGV);
      }
      float tm = m;
#pragma unroll
      for (int kk=0;kk<8;++kk) tm = fmaxf(tm, sc[kk]);
      float alpha = __expf(m - tm);
      l *= alpha;
#pragma unroll
      for (int d=0; d<64; ++d) acc[d] *= alpha;
#pragma unroll
      for (int kk=0;kk<8;++kk){
        int k = kt*8+kk;
        float p = __expf(sc[kk]-tm);
        l += p;
#pragma unroll
        for (int j=0;j<16;++j){
          float4 vv = *(const float4*)(&Vs[k][4*j]);
          acc[4*j]   += p*vv.x;
          acc[4*j+1] += p*vv.y;
          acc[4*j+2] += p*vv.z;
          acc[4*j+3] += p*vv.w;
        }
      }
      m = tm;
    }
  }
  int p = (((b*Hv + h)*2 + g)*8 + chunk)*BLKv + tid;
  Pm[p] = m; Pl[p] = l;
#pragma unroll
  for (int j=0;j<16;++j){
    float4 r; r.x=acc[4*j]; r.y=acc[4*j+1]; r.z=acc[4*j+2]; r.w=acc[4*j+3];
    *(float4*)(&Pacc[(size_t)p*64 + 4*j]) = r;
  }
}

// ---------------- merge global partials into out rows of blocks 0 and NB-1 ----------------
__global__ __launch_bounds__(64) void k_attn_merge(const float* __restrict__ Pm, const float* __restrict__ Pl,
    const float* __restrict__ Pacc, float* __restrict__ out)
{
  int g = blockIdx.x, h = blockIdx.y, b = blockIdx.z;
  int tid = threadIdx.x;   // = d
  int qblk = g ? (NBv-1) : 0;
  for (int q=0; q<BLKv; ++q){
    int base = (((b*Hv + h)*2 + g)*8)*BLKv + q;
    float M = -1e30f;
#pragma unroll
    for (int c=0;c<8;++c) M = fmaxf(M, Pm[base + c*BLKv]);
    float Lc = 0.f, o = 0.f;
#pragma unroll
    for (int c=0;c<8;++c){
      float e = __expf(Pm[base + c*BLKv] - M);
      Lc += Pl[base + c*BLKv]*e;
      o  += e * Pacc[(size_t)(base + c*BLKv)*64 + tid];
    }
    out[((size_t)(b*Sv + qblk*BLKv + q))*Dv + h*DHv + tid] = o / Lc;
  }
}

// ---------------- question_mask dtype detector: flag=1 if stored as 1-byte bools ----------------
__global__ __launch_bounds__(256) void k_qdetect(const unsigned char* __restrict__ qm, int* __restrict__ flag)
{
  int tid = threadIdx.x;
  int any = 0;
  for (int i2 = tid; i2 < Bv*Sv; i2 += 256){
    if ((i2 & 3) != 0) any |= (int)qm[i2];
  }
  float r = blockSum256((float)any);
  if (tid==0) *flag = (r > 0.f) ? 1 : 0;
}

// ---------------- QA logits: 2 dot-products of 768 per row + question_mask zeroing ----------------
__global__ __launch_bounds__(64) void k_logits(const float* __restrict__ X, const float* __restrict__ qaw,
    const float* __restrict__ qab, const void* __restrict__ qmask, const int* __restrict__ qflag,
    float* __restrict__ outbuf)
{
  int row = blockIdx.x;
  int tid = threadIdx.x;
  const float* xr = X + (size_t)row*Dv;
  float s0=0.f, s1=0.f;
#pragma unroll
  for (int j=0;j<12;++j){
    int d = tid + j*64;
    float x = xr[d];
    s0 += x*qaw[2*d];
    s1 += x*qaw[2*d+1];
  }
  s0 = waveSum(s0); s1 = waveSum(s1);
  if (tid==0){
    s0 += qab[0]; s1 += qab[1];
    int qm;
    if (*qflag) qm = (int)((const unsigned char*)qmask)[row];
    else        qm = ((const int*)qmask)[row];
    if (qm){ s0 = 0.f; s1 = 0.f; }
    outbuf[1 + row] = s0;
    outbuf[1 + Bv*Sv + row] = s1;
  }
}

// ---------------- CE loss over start/end logits ----------------
__global__ __launch_bounds__(256) void k_ce(float* __restrict__ outbuf, const int* __restrict__ sp, const int* __restrict__ ep)
{
  __shared__ float nbuf[4];
  __shared__ int vbuf[4];
  int tid = threadIdx.x;
  for (int rowi=0; rowi<4; ++rowi){
    int t = rowi>>1, b = rowi&1;
    const float* lg = outbuf + 1 + t*(Bv*Sv) + b*Sv;
    float mx = -1e30f;
    for (int s2=tid; s2<Sv; s2+=256) mx = fmaxf(mx, lg[s2]);
    mx = blockMax256(mx);
    float se = 0.f;
    for (int s2=tid; s2<Sv; s2+=256) se += __expf(lg[s2]-mx);
    se = blockSum256(se);
    if (tid==0){
      int lab = t ? ep[b] : sp[b];
      if (lab>=0 && lab<Sv){ nbuf[rowi] = -(lg[lab]-mx-logf(se)); vbuf[rowi]=1; }
      else { nbuf[rowi]=0.f; vbuf[rowi]=0; }
    }
  }
  __syncthreads();
  if (tid==0){
    float c0 = (float)(vbuf[0]+vbuf[1]); if (c0<1.f) c0=1.f;
    float c1 = (float)(vbuf[2]+vbuf[3]); if (c1<1.f) c1=1.f;
    outbuf[0] = 0.5f*((nbuf[0]+nbuf[1])/c0 + (nbuf[2]+nbuf[3])/c1);
  }
}

extern "C" void kernel_launch(void* const* d_in, const int* in_sizes, int n_in,
                              void* d_out, int out_size, void* d_ws, size_t ws_size,
                              hipStream_t stream) {
  (void)in_sizes; (void)n_in; (void)out_size; (void)ws_size;
  const int*   input_ids = (const int*)d_in[0];
  const int*   amask     = (const int*)d_in[1];
  const void*  qmask     = d_in[2];            // bool — dtype detected at runtime
  const int*   sp        = (const int*)d_in[3];
  const int*   ep        = (const int*)d_in[4];
  const int*   rnd       = (const int*)d_in[5];
  const float* wemb      = (const float*)d_in[6];
  const float* pemb      = (const float*)d_in[7];
  const float* elns      = (const float*)d_in[8];
  const float* elnb      = (const float*)d_in[9];
  const float* Wq = (const float*)d_in[10]; const float* bq = (const float*)d_in[11];
  const float* Wk = (const float*)d_in[12]; const float* bk = (const float*)d_in[13];
  const float* Wv = (const float*)d_in[14]; const float* bv = (const float*)d_in[15];
  const float* Wo = (const float*)d_in[16]; const float* bo = (const float*)d_in[17];
  const float* ln1s = (const float*)d_in[18]; const float* ln1b = (const float*)d_in[19];
  const float* Wff1 = (const float*)d_in[20]; const float* bff1 = (const float*)d_in[21];
  const float* Wff2 = (const float*)d_in[22]; const float* bff2 = (const float*)d_in[23];
  const float* ln2s = (const float*)d_in[24]; const float* ln2b = (const float*)d_in[25];
  const float* d1w = (const float*)d_in[26]; const float* d1b = (const float*)d_in[27];
  const float* d2w = (const float*)d_in[28]; const float* d2b = (const float*)d_in[29];
  const float* hlns = (const float*)d_in[30]; const float* hlnb = (const float*)d_in[31];
  const float* qaw = (const float*)d_in[32]; const float* qab = (const float*)d_in[33];
  float* outf = (float*)d_out;

  float* ws = (float*)d_ws;
  const size_t MD = (size_t)(Bv*Sv)*Dv;          // 6291456
  float* X  = ws;
  float* Qb = ws + MD;
  float* Kb = ws + 2*MD;
  float* Vb = ws + 3*MD;
  float* T2 = ws + 4*MD;
  float* T1 = ws + 5*MD;                          // 8192*3072
  float* Pm = T1 + (size_t)(Bv*Sv)*FFv;
  float* Pl = Pm + (size_t)Bv*Hv*2*8*BLKv;        // 24576
  float* Pacc = Pl + (size_t)Bv*Hv*2*8*BLKv;      // 24576*64
  int* qflag = (int*)(Pacc + (size_t)Bv*Hv*2*8*BLKv*64);

  const int Mrows = Bv*Sv;                        // 8192

  k_qdetect<<<1, 256, 0, stream>>>((const unsigned char*)qmask, qflag);
  k_embed_ln<<<Mrows, 256, 0, stream>>>(input_ids, wemb, pemb, elns, elnb, X);

  for (int l=0; l<Lv; ++l){
    const float* wq = Wq + (size_t)l*Dv*Dv;  const float* bql = bq + (size_t)l*Dv;
    const float* wk = Wk + (size_t)l*Dv*Dv;  const float* bkl = bk + (size_t)l*Dv;
    const float* wv = Wv + (size_t)l*Dv*Dv;  const float* bvl = bv + (size_t)l*Dv;
    const float* wo = Wo + (size_t)l*Dv*Dv;  const float* bol = bo + (size_t)l*Dv;

    k_gemm<<<dim3(Dv/128, Mrows/128), 256, 0, stream>>>(X, wq, bql, Qb, Mrows, Dv, Dv, 0);
    k_gemm<<<dim3(Dv/128, Mrows/128), 256, 0, stream>>>(X, wk, bkl, Kb, Mrows, Dv, Dv, 0);
    k_gemm<<<dim3(Dv/128, Mrows/128), 256, 0, stream>>>(X, wv, bvl, Vb, Mrows, Dv, Dv, 0);

    k_attn_sparse<<<dim3(NBv-2, Hv, Bv), 64, 0, stream>>>(Qb, Kb, Vb, amask, rnd, T2);
    k_attn_global<<<dim3(16, Hv, Bv), 64, 0, stream>>>(Qb, Kb, Vb, amask, Pm, Pl, Pacc);
    k_attn_merge<<<dim3(2, Hv, Bv), 64, 0, stream>>>(Pm, Pl, Pacc, T2);

    k_gemm<<<dim3(Dv/128, Mrows/128), 256, 0, stream>>>(T2, wo, bol, Qb, Mrows, Dv, Dv, 0);
    k_ln<<<Mrows, 256, 0, stream>>>(X, Qb, 1, ln1s + (size_t)l*Dv, ln1b + (size_t)l*Dv, X);

    k_gemm<<<dim3(FFv/128, Mrows/128), 256, 0, stream>>>(X, Wff1 + (size_t)l*Dv*FFv, bff1 + (size_t)l*FFv, T1, Mrows, FFv, Dv, 1);
    k_gemm<<<dim3(Dv/128, Mrows/128), 256, 0, stream>>>(T1, Wff2 + (size_t)l*FFv*Dv, bff2 + (size_t)l*Dv, T2, Mrows, Dv, FFv, 0);
    k_ln<<<Mrows, 256, 0, stream>>>(X, T2, 1, ln2s + (size_t)l*Dv, ln2b + (size_t)l*Dv, X);
  }

  k_gemm<<<dim3(FFv/128, Mrows/128), 256, 0, stream>>>(X, d1w, d1b, T1, Mrows, FFv, Dv, 1);
  k_gemm<<<dim3(Dv/128, Mrows/128), 256, 0, stream>>>(T1, d2w, d2b, T2, Mrows, Dv, FFv, 0);
  k_ln<<<Mrows, 256, 0, stream>>>(T2, nullptr, 0, hlns, hlnb, X);

  k_logits<<<Mrows, 64, 0, stream>>>(X, qaw, qab, qmask, qflag, outf);
  k_ce<<<1, 256, 0, stream>>>(outf, sp, ep);
}

// Round 2
// 7031.747 us; speedup vs baseline: 2.1062x; 2.1062x over previous
//
#include <hip/hip_runtime.h>
#include <math.h>

#define Bv   2
#define Sv   4096
#define Dv   768
#define Hv   12
#define DHv  64
#define BLKv 64
#define NBv  64
#define FFv  3072
#define Lv   4
#define NEGV (-1000000000.0f)

typedef unsigned short u16;
typedef short s16x8 __attribute__((ext_vector_type(8)));
typedef float f32x4 __attribute__((ext_vector_type(4)));
union U16x8 { uint4 u; s16x8 s; };

// ---------------- helpers ----------------
__device__ __forceinline__ float waveSum(float v){
#pragma unroll
  for (int o=32;o>0;o>>=1) v += __shfl_xor(v, o, 64);
  return v;
}
__device__ __forceinline__ float waveMax(float v){
#pragma unroll
  for (int o=32;o>0;o>>=1) v = fmaxf(v, __shfl_xor(v, o, 64));
  return v;
}
__device__ __forceinline__ float blockSum256(float v){
  __shared__ float sbS[4];
  int tid = threadIdx.x;
  v = waveSum(v);
  if ((tid&63)==0) sbS[tid>>6] = v;
  __syncthreads();
  float r = sbS[0]+sbS[1]+sbS[2]+sbS[3];
  __syncthreads();
  return r;
}
__device__ __forceinline__ float blockMax256(float v){
  __shared__ float sbM[4];
  int tid = threadIdx.x;
  v = waveMax(v);
  if ((tid&63)==0) sbM[tid>>6] = v;
  __syncthreads();
  float r = fmaxf(fmaxf(sbM[0],sbM[1]), fmaxf(sbM[2],sbM[3]));
  __syncthreads();
  return r;
}
__device__ __forceinline__ float gelu_f(float x){
  return 0.5f*x*(1.0f + tanhf(0.7978845608f*(x + 0.044715f*x*x*x)));
}
// fp32 -> bf16 bits, round-to-nearest-even
__device__ __forceinline__ u16 f2bf(float f){
  unsigned u = __float_as_uint(f);
  unsigned r = (u + 0x7fffu + ((u>>16)&1u)) >> 16;
  return (u16)r;
}
// bf16 pair unpack from a packed uint
__device__ __forceinline__ float blo(unsigned u){ return __uint_as_float(u << 16); }
__device__ __forceinline__ float bhi(unsigned u){ return __uint_as_float(u & 0xffff0000u); }

__device__ __forceinline__ void gl2lds16(const void* g, void* l){
  __builtin_amdgcn_global_load_lds((const __attribute__((address_space(1))) void*)g,
                                   (__attribute__((address_space(3))) void*)l, 16, 0, 0);
}

// ---------------- weight transpose+convert: dst[n*K+k] = bf16(src[k*N+n]) ----------------
__global__ __launch_bounds__(256) void k_transw(const float* __restrict__ src, u16* __restrict__ dst,
    int K, int N, size_t ss, size_t ds)
{
  __shared__ float t[32][33];
  src += (size_t)blockIdx.z * ss;
  dst += (size_t)blockIdx.z * ds;
  int n0 = blockIdx.x*32, k0 = blockIdx.y*32;
  int tx = threadIdx.x, ty = threadIdx.y;
#pragma unroll
  for (int r=0;r<4;++r) t[ty + r*8][tx] = src[(size_t)(k0+ty+r*8)*N + n0 + tx];
  __syncthreads();
#pragma unroll
  for (int r=0;r<4;++r) dst[(size_t)(n0+ty+r*8)*K + k0 + tx] = f2bf(t[tx][ty + r*8]);
}

// ---------------- embedding + LN (fp32 X + bf16 Xb) ----------------
__global__ __launch_bounds__(256) void k_embed_ln(const int* __restrict__ ids,
    const float* __restrict__ wemb, const float* __restrict__ pemb,
    const float* __restrict__ gam, const float* __restrict__ bet,
    float* __restrict__ X, u16* __restrict__ Xb)
{
  int row = blockIdx.x;
  int s = row & (Sv-1);
  int tid = threadIdx.x;
  int id = ids[row];
  float v[3];
#pragma unroll
  for (int j=0;j<3;++j){
    int c = tid + j*256;
    v[j] = wemb[(size_t)id*Dv + c] + pemb[(size_t)s*Dv + c];
  }
  float mean = blockSum256(v[0]+v[1]+v[2]) * (1.0f/Dv);
  float var = 0.f;
#pragma unroll
  for (int j=0;j<3;++j){ float t = v[j]-mean; var += t*t; }
  var = blockSum256(var) * (1.0f/Dv);
  float rs = rsqrtf(var + 1e-12f);
#pragma unroll
  for (int j=0;j<3;++j){
    int c = tid + j*256;
    float o = (v[j]-mean)*rs*gam[c] + bet[c];
    X[(size_t)row*Dv + c] = o;
    Xb[(size_t)row*Dv + c] = f2bf(o);
  }
}

// ---------------- LN (+optional residual), fp32 out + optional bf16 out ----------------
__global__ __launch_bounds__(256) void k_ln(const float* __restrict__ xin, const float* __restrict__ res,
    int has_res, const float* __restrict__ gam, const float* __restrict__ bet,
    float* __restrict__ out, u16* __restrict__ outb)
{
  int row = blockIdx.x;
  int tid = threadIdx.x;
  float v[3];
#pragma unroll
  for (int j=0;j<3;++j){
    int c = tid + j*256;
    float t = xin[(size_t)row*Dv + c];
    if (has_res) t += res[(size_t)row*Dv + c];
    v[j] = t;
  }
  float mean = blockSum256(v[0]+v[1]+v[2]) * (1.0f/Dv);
  float var = 0.f;
#pragma unroll
  for (int j=0;j<3;++j){ float t = v[j]-mean; var += t*t; }
  var = blockSum256(var) * (1.0f/Dv);
  float rs = rsqrtf(var + 1e-12f);
#pragma unroll
  for (int j=0;j<3;++j){
    int c = tid + j*256;
    float o = (v[j]-mean)*rs*gam[c] + bet[c];
    out[(size_t)row*Dv + c] = o;
    if (outb) outb[(size_t)row*Dv + c] = f2bf(o);
  }
}

// ---------------- bf16 MFMA GEMM: C[M,N] = A[M,K] @ Bt[N,K]^T + bias ----------------
// 128x128 tile, BK=64, 256 thr (4 waves of 64x64), global_load_lds staging,
// XOR-swizzled 16B granules in LDS so ds_read_b128 frag loads are 2-way (free).
__device__ __forceinline__ void gemm_body(const u16* __restrict__ A, const u16* __restrict__ Bt,
    const float* __restrict__ bias, float* __restrict__ outf, u16* __restrict__ outb,
    int N, int K, int act)
{
  __shared__ u16 AsS[8192];   // 128 rows x 64 k (8 granules/row, swizzled)
  __shared__ u16 BsS[8192];
  const int tid = threadIdx.x;
  const int lane = tid & 63, wv = tid >> 6;
  const int wm = wv >> 1, wn = wv & 1;
  const int low = lane & 15, quad = lane >> 4;
  const int bm = blockIdx.y << 7, bn = blockIdx.x << 7;

  f32x4 zero = {0.f,0.f,0.f,0.f};
  f32x4 acc[4][4];
#pragma unroll
  for (int a=0;a<4;++a)
#pragma unroll
    for (int b=0;b<4;++b) acc[a][b] = zero;

  for (int k0=0; k0<K; k0+=64){
    __syncthreads();
#pragma unroll
    for (int i=0;i<4;++i){
      int G = i*256 + wv*64 + lane;        // granule index 0..1023
      int m = G >> 3, s = G & 7;
      int g = s ^ (m & 7);                 // inverse swizzle -> global k-granule
      gl2lds16(A  + (size_t)(bm+m)*K + k0 + (g<<3), (char*)AsS + (size_t)(i*256 + wv*64)*16);
      gl2lds16(Bt + (size_t)(bn+m)*K + k0 + (g<<3), (char*)BsS + (size_t)(i*256 + wv*64)*16);
    }
    __syncthreads();
#pragma unroll
    for (int kk=0;kk<2;++kk){
      U16x8 af[4], bf[4];
      int g = kk*4 + quad;
#pragma unroll
      for (int t=0;t<4;++t){
        int ma = wm*64 + t*16 + low;
        af[t].u = *(const uint4*)((const char*)AsS + (size_t)((ma<<3) + (g ^ (ma&7)))*16);
        int nb2 = wn*64 + t*16 + low;
        bf[t].u = *(const uint4*)((const char*)BsS + (size_t)((nb2<<3) + (g ^ (nb2&7)))*16);
      }
#pragma unroll
      for (int tm=0;tm<4;++tm)
#pragma unroll
        for (int tn=0;tn<4;++tn)
          acc[tm][tn] = __builtin_amdgcn_mfma_f32_16x16x32_bf16(af[tm].s, bf[tn].s, acc[tm][tn], 0,0,0);
    }
  }
  // epilogue: C/D layout col=lane&15, row=quad*4+reg (verified m89/m91)
#pragma unroll
  for (int tm=0;tm<4;++tm){
    int row = bm + wm*64 + tm*16 + quad*4;
#pragma unroll
    for (int tn=0;tn<4;++tn){
      int col = bn + wn*64 + tn*16 + low;
      float bb = bias[col];
#pragma unroll
      for (int r=0;r<4;++r){
        float c = acc[tm][tn][r] + bb;
        if (act) c = gelu_f(c);
        if (outb) outb[(size_t)(row+r)*N + col] = f2bf(c);
        else      outf[(size_t)(row+r)*N + col] = c;
      }
    }
  }
}

__global__ __launch_bounds__(256,2) void k_gemm(const u16* __restrict__ A, const u16* __restrict__ Bt,
    const float* __restrict__ bias, float* __restrict__ outf, u16* __restrict__ outb,
    int N, int K, int act)
{
  gemm_body(A, Bt, bias, outf, outb, N, K, act);
}

__global__ __launch_bounds__(256,2) void k_gemm_qkv(const u16* __restrict__ Xb, const u16* __restrict__ wt,
    const float* __restrict__ bq, const float* __restrict__ bk, const float* __restrict__ bv,
    u16* __restrict__ Qb, u16* __restrict__ Kb, u16* __restrict__ Vb)
{
  int z = blockIdx.z;
  const u16* Bt = wt + (size_t)z*(Dv*Dv);
  const float* bias = (z==0)? bq : (z==1? bk : bv);
  u16* outb = (z==0)? Qb : (z==1? Kb : Vb);
  gemm_body(Xb, Bt, bias, nullptr, outb, Dv, Dv, 0);
}

// ---------------- sparse attention (bf16 Q/K/V in, bf16 out), 1 wave per (b,h,i) ----------------
__global__ __launch_bounds__(64) void k_attn_sparse(const u16* __restrict__ Q, const u16* __restrict__ Kb,
    const u16* __restrict__ Vb, const int* __restrict__ amask, const int* __restrict__ rnd,
    u16* __restrict__ out)
{
  int i = blockIdx.x + 1;
  int h = blockIdx.y, b = blockIdx.z;
  int tid = threadIdx.x;
  __shared__ unsigned KsU[64][36];   // 64 rows x 64 bf16 (+pad to 72), 144B rows
  __shared__ unsigned VsU[64][36];
  __shared__ int Ms[64];
  __shared__ int KBs[8];

  int kvs[8];
  kvs[0]=0; kvs[1]=i-1; kvs[2]=i; kvs[3]=(i+1<NBv? i+1:NBv-1); kvs[4]=NBv-1;
  kvs[5]=rnd[i*3+0]; kvs[6]=rnd[i*3+1]; kvs[7]=rnd[i*3+2];
  int dupmask = 0;
#pragma unroll
  for (int a2=1;a2<8;++a2){
    bool d2=false;
#pragma unroll
    for (int b2=0;b2<a2;++b2) d2 = d2 || (kvs[a2]==kvs[b2]);
    if (d2) dupmask |= (1<<a2);
  }
  if (tid==0){
#pragma unroll
    for (int w=0;w<8;++w) KBs[w]=kvs[w];
  }

  const uint4* qp4 = (const uint4*)(Q + ((size_t)(b*Sv + i*BLKv + tid))*Dv + h*DHv);
  float qreg[64];
#pragma unroll
  for (int j=0;j<8;++j){
    uint4 t = qp4[j];
    qreg[8*j+0]=blo(t.x); qreg[8*j+1]=bhi(t.x);
    qreg[8*j+2]=blo(t.y); qreg[8*j+3]=bhi(t.y);
    qreg[8*j+4]=blo(t.z); qreg[8*j+5]=bhi(t.z);
    qreg[8*j+6]=blo(t.w); qreg[8*j+7]=bhi(t.w);
  }
  float acc[64];
#pragma unroll
  for (int d=0; d<64; ++d) acc[d]=0.f;
  float m = -1e30f, l = 0.f;

#pragma unroll 1
  for (int w=0; w<8; ++w){
    __syncthreads();
    int kblk = KBs[w];
    const uint4* kp4 = (const uint4*)(Kb + ((size_t)(b*Sv + kblk*BLKv + tid))*Dv + h*DHv);
    const uint4* vp4 = (const uint4*)(Vb + ((size_t)(b*Sv + kblk*BLKv + tid))*Dv + h*DHv);
    uint4* kd = (uint4*)((char*)KsU + tid*144);
    uint4* vd = (uint4*)((char*)VsU + tid*144);
#pragma unroll
    for (int j=0;j<8;++j){ kd[j] = kp4[j]; vd[j] = vp4[j]; }
    Ms[tid] = amask[b*Sv + kblk*BLKv + tid];
    __syncthreads();
    float wbias = ((dupmask>>w)&1) ? NEGV : 0.f;
#pragma unroll 1
    for (int kt=0; kt<8; ++kt){
      float sc[8];
#pragma unroll
      for (int kk=0;kk<8;++kk){
        int k = kt*8+kk;
        const uint4* kr = (const uint4*)((const char*)KsU + k*144);
        float s=0.f;
#pragma unroll
        for (int j=0;j<8;++j){
          uint4 u = kr[j];
          const float* qq = &qreg[8*j];
          s += qq[0]*blo(u.x) + qq[1]*bhi(u.x) + qq[2]*blo(u.y) + qq[3]*bhi(u.y)
             + qq[4]*blo(u.z) + qq[5]*bhi(u.z) + qq[6]*blo(u.w) + qq[7]*bhi(u.w);
        }
        sc[kk] = s*0.125f + wbias + (Ms[k] ? 0.f : NEGV);
      }
      float tm = m;
#pragma unroll
      for (int kk=0;kk<8;++kk) tm = fmaxf(tm, sc[kk]);
      float alpha = __expf(m - tm);
      l *= alpha;
#pragma unroll
      for (int d=0; d<64; ++d) acc[d] *= alpha;
#pragma unroll
      for (int kk=0;kk<8;++kk){
        int k = kt*8+kk;
        float p = __expf(sc[kk]-tm);
        l += p;
        const uint4* vr = (const uint4*)((const char*)VsU + k*144);
#pragma unroll
        for (int j=0;j<8;++j){
          uint4 u = vr[j];
          float* aq = &acc[8*j];
          aq[0]+=p*blo(u.x); aq[1]+=p*bhi(u.x); aq[2]+=p*blo(u.y); aq[3]+=p*bhi(u.y);
          aq[4]+=p*blo(u.z); aq[5]+=p*bhi(u.z); aq[6]+=p*blo(u.w); aq[7]+=p*bhi(u.w);
        }
      }
      m = tm;
    }
  }
  float inv = 1.0f/l;
  unsigned* op = (unsigned*)(out + ((size_t)(b*Sv + i*BLKv + tid))*Dv + h*DHv);
#pragma unroll
  for (int j=0;j<32;++j){
    op[j] = (unsigned)f2bf(acc[2*j]*inv) | ((unsigned)f2bf(acc[2*j+1]*inv) << 16);
  }
}

// ---------------- global attention partials (q blocks 0 & 63 over all keys) ----------------
__global__ __launch_bounds__(64) void k_attn_global(const u16* __restrict__ Q, const u16* __restrict__ Kb,
    const u16* __restrict__ Vb, const int* __restrict__ amask,
    float* __restrict__ Pm, float* __restrict__ Pl, float* __restrict__ Pacc)
{
  int g = blockIdx.x & 1, chunk = blockIdx.x >> 1;
  int h = blockIdx.y, b = blockIdx.z;
  int tid = threadIdx.x;
  __shared__ unsigned KsU[64][36];
  __shared__ unsigned VsU[64][36];
  __shared__ int Ms[64];

  int qblk = g ? (NBv-1) : 0;
  const uint4* qp4 = (const uint4*)(Q + ((size_t)(b*Sv + qblk*BLKv + tid))*Dv + h*DHv);
  float qreg[64];
#pragma unroll
  for (int j=0;j<8;++j){
    uint4 t = qp4[j];
    qreg[8*j+0]=blo(t.x); qreg[8*j+1]=bhi(t.x);
    qreg[8*j+2]=blo(t.y); qreg[8*j+3]=bhi(t.y);
    qreg[8*j+4]=blo(t.z); qreg[8*j+5]=bhi(t.z);
    qreg[8*j+6]=blo(t.w); qreg[8*j+7]=bhi(t.w);
  }
  float acc[64];
#pragma unroll
  for (int d=0; d<64; ++d) acc[d]=0.f;
  float m = -1e30f, l = 0.f;

#pragma unroll 1
  for (int w=0; w<8; ++w){
    __syncthreads();
    int kblk = chunk*8 + w;
    const uint4* kp4 = (const uint4*)(Kb + ((size_t)(b*Sv + kblk*BLKv + tid))*Dv + h*DHv);
    const uint4* vp4 = (const uint4*)(Vb + ((size_t)(b*Sv + kblk*BLKv + tid))*Dv + h*DHv);
    uint4* kd = (uint4*)((char*)KsU + tid*144);
    uint4* vd = (uint4*)((char*)VsU + tid*144);
#pragma unroll
    for (int j=0;j<8;++j){ kd[j] = kp4[j]; vd[j] = vp4[j]; }
    Ms[tid] = amask[b*Sv + kblk*BLKv + tid];
    __syncthreads();
#pragma unroll 1
    for (int kt=0; kt<8; ++kt){
      float sc[8];
#pragma unroll
      for (int kk=0;kk<8;++kk){
        int k = kt*8+kk;
        const uint4* kr = (const uint4*)((const char*)KsU + k*144);
        float s=0.f;
#pragma unroll
        for (int j=0;j<8;++j){
          uint4 u = kr[j];
          const float* qq = &qreg[8*j];
          s += qq[0]*blo(u.x) + qq[1]*bhi(u.x) + qq[2]*blo(u.y) + qq[3]*bhi(u.y)
             + qq[4]*blo(u.z) + qq[5]*bhi(u.z) + qq[6]*blo(u.w) + qq[7]*bhi(u.w);
        }
        sc[kk] = s*0.125f + (Ms[k] ? 0.f : NEGV);
      }
      float tm = m;
#pragma unroll
      for (int kk=0;kk<8;++kk) tm = fmaxf(tm, sc[kk]);
      float alpha = __expf(m - tm);
      l *= alpha;
#pragma unroll
      for (int d=0; d<64; ++d) acc[d] *= alpha;
#pragma unroll
      for (int kk=0;kk<8;++kk){
        int k = kt*8+kk;
        float p = __expf(sc[kk]-tm);
        l += p;
        const uint4* vr = (const uint4*)((const char*)VsU + k*144);
#pragma unroll
        for (int j=0;j<8;++j){
          uint4 u = vr[j];
          float* aq = &acc[8*j];
          aq[0]+=p*blo(u.x); aq[1]+=p*bhi(u.x); aq[2]+=p*blo(u.y); aq[3]+=p*bhi(u.y);
          aq[4]+=p*blo(u.z); aq[5]+=p*bhi(u.z); aq[6]+=p*blo(u.w); aq[7]+=p*bhi(u.w);
        }
      }
      m = tm;
    }
  }
  int p = (((b*Hv + h)*2 + g)*8 + chunk)*BLKv + tid;
  Pm[p] = m; Pl[p] = l;
#pragma unroll
  for (int j=0;j<16;++j){
    float4 r; r.x=acc[4*j]; r.y=acc[4*j+1]; r.z=acc[4*j+2]; r.w=acc[4*j+3];
    *(float4*)(&Pacc[(size_t)p*64 + 4*j]) = r;
  }
}

// ---------------- merge global partials into bf16 out rows of blocks 0 and NB-1 ----------------
__global__ __launch_bounds__(64) void k_attn_merge(const float* __restrict__ Pm, const float* __restrict__ Pl,
    const float* __restrict__ Pacc, u16* __restrict__ out)
{
  int g = blockIdx.x, h = blockIdx.y, b = blockIdx.z;
  int tid = threadIdx.x;   // = d
  int qblk = g ? (NBv-1) : 0;
  for (int q=0; q<BLKv; ++q){
    int base = (((b*Hv + h)*2 + g)*8)*BLKv + q;
    float M = -1e30f;
#pragma unroll
    for (int c=0;c<8;++c) M = fmaxf(M, Pm[base + c*BLKv]);
    float Lc = 0.f, o = 0.f;
#pragma unroll
    for (int c=0;c<8;++c){
      float e = __expf(Pm[base + c*BLKv] - M);
      Lc += Pl[base + c*BLKv]*e;
      o  += e * Pacc[(size_t)(base + c*BLKv)*64 + tid];
    }
    out[((size_t)(b*Sv + qblk*BLKv + q))*Dv + h*DHv + tid] = f2bf(o / Lc);
  }
}

// ---------------- question_mask dtype detector ----------------
__global__ __launch_bounds__(256) void k_qdetect(const unsigned char* __restrict__ qm, int* __restrict__ flag)
{
  int tid = threadIdx.x;
  int any = 0;
  for (int i2 = tid; i2 < Bv*Sv; i2 += 256){
    if ((i2 & 3) != 0) any |= (int)qm[i2];
  }
  float r = blockSum256((float)any);
  if (tid==0) *flag = (r > 0.f) ? 1 : 0;
}

// ---------------- QA logits ----------------
__global__ __launch_bounds__(64) void k_logits(const float* __restrict__ X, const float* __restrict__ qaw,
    const float* __restrict__ qab, const void* __restrict__ qmask, const int* __restrict__ qflag,
    float* __restrict__ outbuf)
{
  int row = blockIdx.x;
  int tid = threadIdx.x;
  const float* xr = X + (size_t)row*Dv;
  float s0=0.f, s1=0.f;
#pragma unroll
  for (int j=0;j<12;++j){
    int d = tid + j*64;
    float x = xr[d];
    s0 += x*qaw[2*d];
    s1 += x*qaw[2*d+1];
  }
  s0 = waveSum(s0); s1 = waveSum(s1);
  if (tid==0){
    s0 += qab[0]; s1 += qab[1];
    int qm;
    if (*qflag) qm = (int)((const unsigned char*)qmask)[row];
    else        qm = ((const int*)qmask)[row];
    if (qm){ s0 = 0.f; s1 = 0.f; }
    outbuf[1 + row] = s0;
    outbuf[1 + Bv*Sv + row] = s1;
  }
}

// ---------------- CE loss ----------------
__global__ __launch_bounds__(256) void k_ce(float* __restrict__ outbuf, const int* __restrict__ sp, const int* __restrict__ ep)
{
  __shared__ float nbuf[4];
  __shared__ int vbuf[4];
  int tid = threadIdx.x;
  for (int rowi=0; rowi<4; ++rowi){
    int t = rowi>>1, b = rowi&1;
    const float* lg = outbuf + 1 + t*(Bv*Sv) + b*Sv;
    float mx = -1e30f;
    for (int s2=tid; s2<Sv; s2+=256) mx = fmaxf(mx, lg[s2]);
    mx = blockMax256(mx);
    float se = 0.f;
    for (int s2=tid; s2<Sv; s2+=256) se += __expf(lg[s2]-mx);
    se = blockSum256(se);
    if (tid==0){
      int lab = t ? ep[b] : sp[b];
      if (lab>=0 && lab<Sv){ nbuf[rowi] = -(lg[lab]-mx-logf(se)); vbuf[rowi]=1; }
      else { nbuf[rowi]=0.f; vbuf[rowi]=0; }
    }
  }
  __syncthreads();
  if (tid==0){
    float c0 = (float)(vbuf[0]+vbuf[1]); if (c0<1.f) c0=1.f;
    float c1 = (float)(vbuf[2]+vbuf[3]); if (c1<1.f) c1=1.f;
    outbuf[0] = 0.5f*((nbuf[0]+nbuf[1])/c0 + (nbuf[2]+nbuf[3])/c1);
  }
}

extern "C" void kernel_launch(void* const* d_in, const int* in_sizes, int n_in,
                              void* d_out, int out_size, void* d_ws, size_t ws_size,
                              hipStream_t stream) {
  (void)in_sizes; (void)n_in; (void)out_size; (void)ws_size;
  const int*   input_ids = (const int*)d_in[0];
  const int*   amask     = (const int*)d_in[1];
  const void*  qmask     = d_in[2];
  const int*   sp        = (const int*)d_in[3];
  const int*   ep        = (const int*)d_in[4];
  const int*   rnd       = (const int*)d_in[5];
  const float* wemb      = (const float*)d_in[6];
  const float* pemb      = (const float*)d_in[7];
  const float* elns      = (const float*)d_in[8];
  const float* elnb      = (const float*)d_in[9];
  const float* Wq = (const float*)d_in[10]; const float* bq = (const float*)d_in[11];
  const float* Wk = (const float*)d_in[12]; const float* bk = (const float*)d_in[13];
  const float* Wv = (const float*)d_in[14]; const float* bv = (const float*)d_in[15];
  const float* Wo = (const float*)d_in[16]; const float* bo = (const float*)d_in[17];
  const float* ln1s = (const float*)d_in[18]; const float* ln1b = (const float*)d_in[19];
  const float* Wff1 = (const float*)d_in[20]; const float* bff1 = (const float*)d_in[21];
  const float* Wff2 = (const float*)d_in[22]; const float* bff2 = (const float*)d_in[23];
  const float* ln2s = (const float*)d_in[24]; const float* ln2b = (const float*)d_in[25];
  const float* d1w = (const float*)d_in[26]; const float* d1b = (const float*)d_in[27];
  const float* d2w = (const float*)d_in[28]; const float* d2b = (const float*)d_in[29];
  const float* hlns = (const float*)d_in[30]; const float* hlnb = (const float*)d_in[31];
  const float* qaw = (const float*)d_in[32]; const float* qab = (const float*)d_in[33];
  float* outf = (float*)d_out;

  // ---- workspace layout (bytes); total ~186.6 MB ----
  char* W = (char*)d_ws;
  u16* wtAll = (u16*)W;                       // 33,030,144 bf16 elems
  u16* wtQKV = wtAll;                         // [L][3][768][768]
  u16* wtO   = wtAll + 7077888;               // [L][768][768]
  u16* wtF1  = wtAll + 9437184;               // [L][3072][768]
  u16* wtF2  = wtAll + 18874368;              // [L][768][3072]
  u16* wtd1  = wtAll + 28311552;              // [3072][768]
  u16* wtd2  = wtAll + 30670848;              // [768][3072]
  size_t o = 66060288;
  float* X  = (float*)(W + o);  o += 25165824;
  u16* Xb   = (u16*)(W + o);    o += 12582912;
  u16* Qb   = (u16*)(W + o);    o += 12582912;
  u16* Kb   = (u16*)(W + o);    o += 12582912;
  u16* Vb   = (u16*)(W + o);    o += 12582912;
  u16* T2b  = (u16*)(W + o);    o += 12582912;
  u16* T1b  = Qb;               // alias: FF hidden (50.3MB) over dead Q/K/V/attn-out
  float* R  = (float*)(W + o);  o += 25165824;
  float* Pm = (float*)(W + o);  o += 98304;
  float* Pl = (float*)(W + o);  o += 98304;
  float* Pacc = (float*)(W + o); o += 6291456;
  int* qflag = (int*)(W + o);

  const int Mrows = Bv*Sv;  // 8192
  dim3 tb(32,8);

  k_qdetect<<<1, 256, 0, stream>>>((const unsigned char*)qmask, qflag);
  // weight transpose+bf16 (dst[n][k] = src[k][n])
  k_transw<<<dim3(24,24,4), tb, 0, stream>>>(Wq, wtQKV + 0,      Dv, Dv, 589824, 1769472);
  k_transw<<<dim3(24,24,4), tb, 0, stream>>>(Wk, wtQKV + 589824, Dv, Dv, 589824, 1769472);
  k_transw<<<dim3(24,24,4), tb, 0, stream>>>(Wv, wtQKV + 1179648,Dv, Dv, 589824, 1769472);
  k_transw<<<dim3(24,24,4), tb, 0, stream>>>(Wo, wtO,            Dv, Dv, 589824, 589824);
  k_transw<<<dim3(96,24,4), tb, 0, stream>>>(Wff1, wtF1, Dv, FFv, 2359296, 2359296);
  k_transw<<<dim3(24,96,4), tb, 0, stream>>>(Wff2, wtF2, FFv, Dv, 2359296, 2359296);
  k_transw<<<dim3(96,24,1), tb, 0, stream>>>(d1w, wtd1, Dv, FFv, 0, 0);
  k_transw<<<dim3(24,96,1), tb, 0, stream>>>(d2w, wtd2, FFv, Dv, 0, 0);

  k_embed_ln<<<Mrows, 256, 0, stream>>>(input_ids, wemb, pemb, elns, elnb, X, Xb);

  for (int l=0; l<Lv; ++l){
    k_gemm_qkv<<<dim3(6,64,3), 256, 0, stream>>>(Xb, wtQKV + (size_t)l*1769472,
        bq + (size_t)l*Dv, bk + (size_t)l*Dv, bv + (size_t)l*Dv, Qb, Kb, Vb);

    k_attn_sparse<<<dim3(NBv-2, Hv, Bv), 64, 0, stream>>>(Qb, Kb, Vb, amask, rnd, T2b);
    k_attn_global<<<dim3(16, Hv, Bv), 64, 0, stream>>>(Qb, Kb, Vb, amask, Pm, Pl, Pacc);
    k_attn_merge<<<dim3(2, Hv, Bv), 64, 0, stream>>>(Pm, Pl, Pacc, T2b);

    k_gemm<<<dim3(6,64), 256, 0, stream>>>(T2b, wtO + (size_t)l*589824, bo + (size_t)l*Dv, R, nullptr, Dv, Dv, 0);
    k_ln<<<Mrows, 256, 0, stream>>>(X, R, 1, ln1s + (size_t)l*Dv, ln1b + (size_t)l*Dv, X, Xb);

    k_gemm<<<dim3(24,64), 256, 0, stream>>>(Xb, wtF1 + (size_t)l*2359296, bff1 + (size_t)l*FFv, nullptr, T1b, FFv, Dv, 1);
    k_gemm<<<dim3(6,64), 256, 0, stream>>>(T1b, wtF2 + (size_t)l*2359296, bff2 + (size_t)l*Dv, R, nullptr, Dv, FFv, 0);
    k_ln<<<Mrows, 256, 0, stream>>>(X, R, 1, ln2s + (size_t)l*Dv, ln2b + (size_t)l*Dv, X, Xb);
  }

  k_gemm<<<dim3(24,64), 256, 0, stream>>>(Xb, wtd1, d1b, nullptr, T1b, FFv, Dv, 1);
  k_gemm<<<dim3(6,64), 256, 0, stream>>>(T1b, wtd2, d2b, R, nullptr, Dv, FFv, 0);
  k_ln<<<Mrows, 256, 0, stream>>>(R, nullptr, 0, hlns, hlnb, X, nullptr);

  k_logits<<<Mrows, 64, 0, stream>>>(X, qaw, qab, qmask, qflag, outf);
  k_ce<<<1, 256, 0, stream>>>(outf, sp, ep);
}

// Round 3
// 1922.696 us; speedup vs baseline: 7.7028x; 3.6572x over previous
//
#include <hip/hip_runtime.h>
#include <math.h>

#define Bv   2
#define Sv   4096
#define Dv   768
#define Hv   12
#define DHv  64
#define BLKv 64
#define NBv  64
#define FFv  3072
#define Lv   4
#define NEGV (-1000000000.0f)

typedef unsigned short u16;
typedef short s16x8 __attribute__((ext_vector_type(8)));
typedef float f32x4 __attribute__((ext_vector_type(4)));
union U16x8 { uint4 u; s16x8 s; };

// ---------------- helpers ----------------
__device__ __forceinline__ float waveSum(float v){
#pragma unroll
  for (int o=32;o>0;o>>=1) v += __shfl_xor(v, o, 64);
  return v;
}
__device__ __forceinline__ float waveMax(float v){
#pragma unroll
  for (int o=32;o>0;o>>=1) v = fmaxf(v, __shfl_xor(v, o, 64));
  return v;
}
__device__ __forceinline__ float blockSum256(float v){
  __shared__ float sbS[4];
  int tid = threadIdx.x;
  v = waveSum(v);
  if ((tid&63)==0) sbS[tid>>6] = v;
  __syncthreads();
  float r = sbS[0]+sbS[1]+sbS[2]+sbS[3];
  __syncthreads();
  return r;
}
__device__ __forceinline__ float blockMax256(float v){
  __shared__ float sbM[4];
  int tid = threadIdx.x;
  v = waveMax(v);
  if ((tid&63)==0) sbM[tid>>6] = v;
  __syncthreads();
  float r = fmaxf(fmaxf(sbM[0],sbM[1]), fmaxf(sbM[2],sbM[3]));
  __syncthreads();
  return r;
}
__device__ __forceinline__ float gelu_f(float x){
  return 0.5f*x*(1.0f + tanhf(0.7978845608f*(x + 0.044715f*x*x*x)));
}
__device__ __forceinline__ u16 f2bf(float f){
  unsigned u = __float_as_uint(f);
  unsigned r = (u + 0x7fffu + ((u>>16)&1u)) >> 16;
  return (u16)r;
}
__device__ __forceinline__ float blo(unsigned u){ return __uint_as_float(u << 16); }
__device__ __forceinline__ float bhi(unsigned u){ return __uint_as_float(u & 0xffff0000u); }

__device__ __forceinline__ void gl2lds16(const void* g, void* l){
  __builtin_amdgcn_global_load_lds((const __attribute__((address_space(1))) void*)g,
                                   (__attribute__((address_space(3))) void*)l, 16, 0, 0);
}

// ---------------- weight transpose+convert: dst[n*K+k] = bf16(src[k*N+n]) ----------------
__global__ __launch_bounds__(256) void k_transw(const float* __restrict__ src, u16* __restrict__ dst,
    int K, int N, size_t ss, size_t ds)
{
  __shared__ float t[32][33];
  src += (size_t)blockIdx.z * ss;
  dst += (size_t)blockIdx.z * ds;
  int n0 = blockIdx.x*32, k0 = blockIdx.y*32;
  int tx = threadIdx.x, ty = threadIdx.y;
#pragma unroll
  for (int r=0;r<4;++r) t[ty + r*8][tx] = src[(size_t)(k0+ty+r*8)*N + n0 + tx];
  __syncthreads();
#pragma unroll
  for (int r=0;r<4;++r) dst[(size_t)(n0+ty+r*8)*K + k0 + tx] = f2bf(t[tx][ty + r*8]);
}

// ---------------- embedding + LN (fp32 X + bf16 Xb) ----------------
__global__ __launch_bounds__(256) void k_embed_ln(const int* __restrict__ ids,
    const float* __restrict__ wemb, const float* __restrict__ pemb,
    const float* __restrict__ gam, const float* __restrict__ bet,
    float* __restrict__ X, u16* __restrict__ Xb)
{
  int row = blockIdx.x;
  int s = row & (Sv-1);
  int tid = threadIdx.x;
  int id = ids[row];
  float v[3];
#pragma unroll
  for (int j=0;j<3;++j){
    int c = tid + j*256;
    v[j] = wemb[(size_t)id*Dv + c] + pemb[(size_t)s*Dv + c];
  }
  float mean = blockSum256(v[0]+v[1]+v[2]) * (1.0f/Dv);
  float var = 0.f;
#pragma unroll
  for (int j=0;j<3;++j){ float t = v[j]-mean; var += t*t; }
  var = blockSum256(var) * (1.0f/Dv);
  float rs = rsqrtf(var + 1e-12f);
#pragma unroll
  for (int j=0;j<3;++j){
    int c = tid + j*256;
    float o = (v[j]-mean)*rs*gam[c] + bet[c];
    X[(size_t)row*Dv + c] = o;
    Xb[(size_t)row*Dv + c] = f2bf(o);
  }
}

// ---------------- LN (+optional residual), fp32 out + optional bf16 out ----------------
__global__ __launch_bounds__(256) void k_ln(const float* __restrict__ xin, const float* __restrict__ res,
    int has_res, const float* __restrict__ gam, const float* __restrict__ bet,
    float* __restrict__ out, u16* __restrict__ outb)
{
  int row = blockIdx.x;
  int tid = threadIdx.x;
  float v[3];
#pragma unroll
  for (int j=0;j<3;++j){
    int c = tid + j*256;
    float t = xin[(size_t)row*Dv + c];
    if (has_res) t += res[(size_t)row*Dv + c];
    v[j] = t;
  }
  float mean = blockSum256(v[0]+v[1]+v[2]) * (1.0f/Dv);
  float var = 0.f;
#pragma unroll
  for (int j=0;j<3;++j){ float t = v[j]-mean; var += t*t; }
  var = blockSum256(var) * (1.0f/Dv);
  float rs = rsqrtf(var + 1e-12f);
#pragma unroll
  for (int j=0;j<3;++j){
    int c = tid + j*256;
    float o = (v[j]-mean)*rs*gam[c] + bet[c];
    out[(size_t)row*Dv + c] = o;
    if (outb) outb[(size_t)row*Dv + c] = f2bf(o);
  }
}

// ---------------- bf16 MFMA GEMM: C[M,N] = A[M,K] @ Bt[N,K]^T + bias ----------------
__device__ __forceinline__ void gemm_body(const u16* __restrict__ A, const u16* __restrict__ Bt,
    const float* __restrict__ bias, float* __restrict__ outf, u16* __restrict__ outb,
    int N, int K, int act)
{
  __shared__ u16 AsS[8192];
  __shared__ u16 BsS[8192];
  const int tid = threadIdx.x;
  const int lane = tid & 63, wv = tid >> 6;
  const int wm = wv >> 1, wn = wv & 1;
  const int low = lane & 15, quad = lane >> 4;
  const int bm = blockIdx.y << 7, bn = blockIdx.x << 7;

  f32x4 zero = {0.f,0.f,0.f,0.f};
  f32x4 acc[4][4];
#pragma unroll
  for (int a=0;a<4;++a)
#pragma unroll
    for (int b=0;b<4;++b) acc[a][b] = zero;

  for (int k0=0; k0<K; k0+=64){
    __syncthreads();
#pragma unroll
    for (int i=0;i<4;++i){
      int G = i*256 + wv*64 + lane;
      int m = G >> 3, s = G & 7;
      int g = s ^ (m & 7);
      gl2lds16(A  + (size_t)(bm+m)*K + k0 + (g<<3), (char*)AsS + (size_t)(i*256 + wv*64)*16);
      gl2lds16(Bt + (size_t)(bn+m)*K + k0 + (g<<3), (char*)BsS + (size_t)(i*256 + wv*64)*16);
    }
    __syncthreads();
#pragma unroll
    for (int kk=0;kk<2;++kk){
      U16x8 af[4], bf[4];
      int g = kk*4 + quad;
#pragma unroll
      for (int t=0;t<4;++t){
        int ma = wm*64 + t*16 + low;
        af[t].u = *(const uint4*)((const char*)AsS + (size_t)((ma<<3) + (g ^ (ma&7)))*16);
        int nb2 = wn*64 + t*16 + low;
        bf[t].u = *(const uint4*)((const char*)BsS + (size_t)((nb2<<3) + (g ^ (nb2&7)))*16);
      }
#pragma unroll
      for (int tm=0;tm<4;++tm)
#pragma unroll
        for (int tn=0;tn<4;++tn)
          acc[tm][tn] = __builtin_amdgcn_mfma_f32_16x16x32_bf16(af[tm].s, bf[tn].s, acc[tm][tn], 0,0,0);
    }
  }
#pragma unroll
  for (int tm=0;tm<4;++tm){
    int row = bm + wm*64 + tm*16 + quad*4;
#pragma unroll
    for (int tn=0;tn<4;++tn){
      int col = bn + wn*64 + tn*16 + low;
      float bb = bias[col];
#pragma unroll
      for (int r=0;r<4;++r){
        float c = acc[tm][tn][r] + bb;
        if (act) c = gelu_f(c);
        if (outb) outb[(size_t)(row+r)*N + col] = f2bf(c);
        else      outf[(size_t)(row+r)*N + col] = c;
      }
    }
  }
}

__global__ __launch_bounds__(256,2) void k_gemm(const u16* __restrict__ A, const u16* __restrict__ Bt,
    const float* __restrict__ bias, float* __restrict__ outf, u16* __restrict__ outb,
    int N, int K, int act)
{
  gemm_body(A, Bt, bias, outf, outb, N, K, act);
}

__global__ __launch_bounds__(256,2) void k_gemm_qkv(const u16* __restrict__ Xb, const u16* __restrict__ wt,
    const float* __restrict__ bq, const float* __restrict__ bk, const float* __restrict__ bv,
    u16* __restrict__ Qb, u16* __restrict__ Kb, u16* __restrict__ Vb)
{
  int z = blockIdx.z;
  const u16* Bt = wt + (size_t)z*(Dv*Dv);
  const float* bias = (z==0)? bq : (z==1? bk : bv);
  u16* outb = (z==0)? Qb : (z==1? Kb : Vb);
  gemm_body(Xb, Bt, bias, nullptr, outb, Dv, Dv, 0);
}

// ================= MFMA attention =================
// One 256-thr block per (b,h,qblock[,chunk]). 512 gathered keys.
// LDS: Ks[512][72] (73728B) staged natural; Vt[64][536] (68608B) transposed;
// biasS[512] f32 (2048B). P (bf16, [64][536]) reuses the Ks region after barrier.
#define KPAD 72
#define VPAD 536
#define SM_KS    0
#define SM_VT    73728
#define SM_BIAS  (73728 + 68608)
#define SM_TOTAL (73728 + 68608 + 2048)

// MODE 0: sparse (normalized bf16 out). MODE 1: global partials (Pm/Pl/Pacc).
template<int MODE>
__device__ __forceinline__ void attn_mfma_body(
    const u16* __restrict__ Qg, const u16* __restrict__ Kg, const u16* __restrict__ Vg,
    const int* __restrict__ amask, const int* kbs, int dupmask,
    int b, int h, int qblk,
    u16* __restrict__ out, float* __restrict__ Pm, float* __restrict__ Pl,
    float* __restrict__ Pacc, int pbase)
{
  __shared__ __align__(16) char smem[SM_TOTAL];
  u16* Ks = (u16*)(smem + SM_KS);
  u16* Vt = (u16*)(smem + SM_VT);
  float* biasS = (float*)(smem + SM_BIAS);
  u16* Pb = (u16*)(smem + SM_KS);   // reused after barrier

  const int tid = threadIdx.x;

  // ---- stage K (coalesced global reads, aligned b128 LDS writes) ----
#pragma unroll
  for (int it=0; it<16; ++it){
    int task = tid + it*256;
    int d8 = task & 7, key = task >> 3;
    int gr = b*Sv + kbs[key>>6]*BLKv + (key&63);
    uint4 t = *(const uint4*)(Kg + (size_t)gr*Dv + h*DHv + d8*8);
    *(uint4*)(Ks + key*KPAD + d8*8) = t;
  }
  // ---- stage V transposed (lane==key -> conflict-free scalar LDS writes) ----
#pragma unroll
  for (int it=0; it<16; ++it){
    int key = (tid&63) + 64*(it&7);
    int d8 = (tid>>6) + 4*(it>>3);
    int gr = b*Sv + kbs[key>>6]*BLKv + (key&63);
    uint4 t = *(const uint4*)(Vg + (size_t)gr*Dv + h*DHv + d8*8);
    unsigned uu[4] = {t.x, t.y, t.z, t.w};
#pragma unroll
    for (int jj=0;jj<4;++jj){
      Vt[(d8*8 + 2*jj  )*VPAD + key] = (u16)(uu[jj] & 0xffffu);
      Vt[(d8*8 + 2*jj+1)*VPAD + key] = (u16)(uu[jj] >> 16);
    }
  }
  // ---- per-key bias (amask + dup) ----
  for (int t2 = tid; t2 < 512; t2 += 256){
    int w = t2 >> 6;
    float bb = amask[b*Sv + kbs[w]*BLKv + (t2&63)] ? 0.f : NEGV;
    if ((dupmask>>w) & 1) bb += NEGV;
    biasS[t2] = bb;
  }
  __syncthreads();

  const int lane = tid & 63, wv = tid >> 6;
  const int low = lane & 15, quad = lane >> 4;

  // ---- Q A-frags direct from global ----
  U16x8 aq[2];
  const u16* qbase = Qg + ((size_t)(b*Sv + qblk*BLKv + wv*16 + low))*Dv + h*DHv;
  aq[0].u = *(const uint4*)(qbase + quad*8);
  aq[1].u = *(const uint4*)(qbase + 32 + quad*8);

  // ---- scores: each wave owns 16 q-rows x all 512 keys ----
  f32x4 S[32];
#pragma unroll
  for (int nt=0; nt<32; ++nt){
    U16x8 b0, b1;
    b0.u = *(const uint4*)(Ks + (nt*16+low)*KPAD + quad*8);
    b1.u = *(const uint4*)(Ks + (nt*16+low)*KPAD + 32 + quad*8);
    f32x4 c = {0.f,0.f,0.f,0.f};
    c = __builtin_amdgcn_mfma_f32_16x16x32_bf16(aq[0].s, b0.s, c, 0,0,0);
    c = __builtin_amdgcn_mfma_f32_16x16x32_bf16(aq[1].s, b1.s, c, 0,0,0);
    S[nt] = c;
  }

  // ---- softmax (rows = wv*16 + quad*4 + r; reduce over 16-lane quad group) ----
  float mr[4] = {-1e30f,-1e30f,-1e30f,-1e30f};
  float lr[4] = {0.f,0.f,0.f,0.f};
#pragma unroll
  for (int nt=0; nt<32; ++nt){
    float bb = biasS[nt*16 + low];
#pragma unroll
    for (int r=0;r<4;++r){
      float s = S[nt][r]*0.125f + bb;
      S[nt][r] = s;
      mr[r] = fmaxf(mr[r], s);
    }
  }
#pragma unroll
  for (int r=0;r<4;++r){
#pragma unroll
    for (int o=1;o<16;o<<=1) mr[r] = fmaxf(mr[r], __shfl_xor(mr[r], o, 64));
  }
#pragma unroll
  for (int nt=0; nt<32; ++nt){
#pragma unroll
    for (int r=0;r<4;++r){
      float p = __expf(S[nt][r] - mr[r]);
      S[nt][r] = p;
      lr[r] += p;
    }
  }
#pragma unroll
  for (int r=0;r<4;++r){
#pragma unroll
    for (int o=1;o<16;o<<=1) lr[r] += __shfl_xor(lr[r], o, 64);
  }

  __syncthreads();   // all Ks reads complete before P overwrites it

  // ---- write P (bf16) ----
#pragma unroll
  for (int r=0;r<4;++r){
    u16* prow = Pb + (size_t)(wv*16 + quad*4 + r)*VPAD + low;
#pragma unroll
    for (int nt=0; nt<32; ++nt) prow[nt*16] = f2bf(S[nt][r]);
  }
  __syncthreads();

  // ---- PV: O = P @ V via P A-frags + V^T B-frags ----
  f32x4 O[4];
#pragma unroll
  for (int n2=0;n2<4;++n2){ f32x4 z={0.f,0.f,0.f,0.f}; O[n2]=z; }
#pragma unroll
  for (int kst=0; kst<16; ++kst){
    U16x8 pa;
    pa.u = *(const uint4*)(Pb + (size_t)(wv*16+low)*VPAD + kst*32 + quad*8);
#pragma unroll
    for (int n2=0; n2<4; ++n2){
      U16x8 vb;
      vb.u = *(const uint4*)(Vt + (size_t)(n2*16+low)*VPAD + kst*32 + quad*8);
      O[n2] = __builtin_amdgcn_mfma_f32_16x16x32_bf16(pa.s, vb.s, O[n2], 0,0,0);
    }
  }

  // ---- epilogue ----
  if (MODE == 0){
#pragma unroll
    for (int r=0;r<4;++r){
      float inv = 1.0f/lr[r];
      int row = b*Sv + qblk*BLKv + wv*16 + quad*4 + r;
      u16* op = out + (size_t)row*Dv + h*DHv + low;
#pragma unroll
      for (int n2=0;n2<4;++n2) op[n2*16] = f2bf(O[n2][r]*inv);
    }
  } else {
#pragma unroll
    for (int r=0;r<4;++r){
      int p = pbase + wv*16 + quad*4 + r;
      if (low == 0){ Pm[p] = mr[r]; Pl[p] = lr[r]; }
#pragma unroll
      for (int n2=0;n2<4;++n2) Pacc[(size_t)p*64 + n2*16 + low] = O[n2][r];
    }
  }
}

__global__ __launch_bounds__(256,1) void k_attn_sparse(const u16* __restrict__ Qg,
    const u16* __restrict__ Kg, const u16* __restrict__ Vg,
    const int* __restrict__ amask, const int* __restrict__ rnd, u16* __restrict__ out)
{
  int i = blockIdx.x + 1;
  int h = blockIdx.y, b = blockIdx.z;
  int kbs[8];
  kbs[0]=0; kbs[1]=i-1; kbs[2]=i; kbs[3]=(i+1<NBv? i+1 : NBv-1); kbs[4]=NBv-1;
  kbs[5]=rnd[i*3+0]; kbs[6]=rnd[i*3+1]; kbs[7]=rnd[i*3+2];
  int dupmask = 0;
#pragma unroll
  for (int a2=1;a2<8;++a2){
    bool d2=false;
#pragma unroll
    for (int b2=0;b2<a2;++b2) d2 = d2 || (kbs[a2]==kbs[b2]);
    if (d2) dupmask |= (1<<a2);
  }
  attn_mfma_body<0>(Qg, Kg, Vg, amask, kbs, dupmask, b, h, i, out, nullptr, nullptr, nullptr, 0);
}

__global__ __launch_bounds__(256,1) void k_attn_global(const u16* __restrict__ Qg,
    const u16* __restrict__ Kg, const u16* __restrict__ Vg,
    const int* __restrict__ amask,
    float* __restrict__ Pm, float* __restrict__ Pl, float* __restrict__ Pacc)
{
  int g = blockIdx.x & 1, chunk = blockIdx.x >> 1;
  int h = blockIdx.y, b = blockIdx.z;
  int kbs[8];
#pragma unroll
  for (int w=0;w<8;++w) kbs[w] = chunk*8 + w;
  int qblk = g ? (NBv-1) : 0;
  int pbase = (((b*Hv + h)*2 + g)*8 + chunk)*BLKv;
  attn_mfma_body<1>(Qg, Kg, Vg, amask, kbs, 0, b, h, qblk, nullptr, Pm, Pl, Pacc, pbase);
}

// ---------------- merge global partials into bf16 out rows of blocks 0 and NB-1 ----------------
__global__ __launch_bounds__(64) void k_attn_merge(const float* __restrict__ Pm, const float* __restrict__ Pl,
    const float* __restrict__ Pacc, u16* __restrict__ out)
{
  int g = blockIdx.x, h = blockIdx.y, b = blockIdx.z;
  int tid = threadIdx.x;   // = d
  int qblk = g ? (NBv-1) : 0;
  for (int q=0; q<BLKv; ++q){
    int base = (((b*Hv + h)*2 + g)*8)*BLKv + q;
    float M = -1e30f;
#pragma unroll
    for (int c=0;c<8;++c) M = fmaxf(M, Pm[base + c*BLKv]);
    float Lc = 0.f, o = 0.f;
#pragma unroll
    for (int c=0;c<8;++c){
      float e = __expf(Pm[base + c*BLKv] - M);
      Lc += Pl[base + c*BLKv]*e;
      o  += e * Pacc[(size_t)(base + c*BLKv)*64 + tid];
    }
    out[((size_t)(b*Sv + qblk*BLKv + q))*Dv + h*DHv + tid] = f2bf(o / Lc);
  }
}

// ---------------- question_mask dtype detector ----------------
__global__ __launch_bounds__(256) void k_qdetect(const unsigned char* __restrict__ qm, int* __restrict__ flag)
{
  int tid = threadIdx.x;
  int any = 0;
  for (int i2 = tid; i2 < Bv*Sv; i2 += 256){
    if ((i2 & 3) != 0) any |= (int)qm[i2];
  }
  float r = blockSum256((float)any);
  if (tid==0) *flag = (r > 0.f) ? 1 : 0;
}

// ---------------- QA logits ----------------
__global__ __launch_bounds__(64) void k_logits(const float* __restrict__ X, const float* __restrict__ qaw,
    const float* __restrict__ qab, const void* __restrict__ qmask, const int* __restrict__ qflag,
    float* __restrict__ outbuf)
{
  int row = blockIdx.x;
  int tid = threadIdx.x;
  const float* xr = X + (size_t)row*Dv;
  float s0=0.f, s1=0.f;
#pragma unroll
  for (int j=0;j<12;++j){
    int d = tid + j*64;
    float x = xr[d];
    s0 += x*qaw[2*d];
    s1 += x*qaw[2*d+1];
  }
  s0 = waveSum(s0); s1 = waveSum(s1);
  if (tid==0){
    s0 += qab[0]; s1 += qab[1];
    int qm;
    if (*qflag) qm = (int)((const unsigned char*)qmask)[row];
    else        qm = ((const int*)qmask)[row];
    if (qm){ s0 = 0.f; s1 = 0.f; }
    outbuf[1 + row] = s0;
    outbuf[1 + Bv*Sv + row] = s1;
  }
}

// ---------------- CE loss ----------------
__global__ __launch_bounds__(256) void k_ce(float* __restrict__ outbuf, const int* __restrict__ sp, const int* __restrict__ ep)
{
  __shared__ float nbuf[4];
  __shared__ int vbuf[4];
  int tid = threadIdx.x;
  for (int rowi=0; rowi<4; ++rowi){
    int t = rowi>>1, b = rowi&1;
    const float* lg = outbuf + 1 + t*(Bv*Sv) + b*Sv;
    float mx = -1e30f;
    for (int s2=tid; s2<Sv; s2+=256) mx = fmaxf(mx, lg[s2]);
    mx = blockMax256(mx);
    float se = 0.f;
    for (int s2=tid; s2<Sv; s2+=256) se += __expf(lg[s2]-mx);
    se = blockSum256(se);
    if (tid==0){
      int lab = t ? ep[b] : sp[b];
      if (lab>=0 && lab<Sv){ nbuf[rowi] = -(lg[lab]-mx-logf(se)); vbuf[rowi]=1; }
      else { nbuf[rowi]=0.f; vbuf[rowi]=0; }
    }
  }
  __syncthreads();
  if (tid==0){
    float c0 = (float)(vbuf[0]+vbuf[1]); if (c0<1.f) c0=1.f;
    float c1 = (float)(vbuf[2]+vbuf[3]); if (c1<1.f) c1=1.f;
    outbuf[0] = 0.5f*((nbuf[0]+nbuf[1])/c0 + (nbuf[2]+nbuf[3])/c1);
  }
}

extern "C" void kernel_launch(void* const* d_in, const int* in_sizes, int n_in,
                              void* d_out, int out_size, void* d_ws, size_t ws_size,
                              hipStream_t stream) {
  (void)in_sizes; (void)n_in; (void)out_size; (void)ws_size;
  const int*   input_ids = (const int*)d_in[0];
  const int*   amask     = (const int*)d_in[1];
  const void*  qmask     = d_in[2];
  const int*   sp        = (const int*)d_in[3];
  const int*   ep        = (const int*)d_in[4];
  const int*   rnd       = (const int*)d_in[5];
  const float* wemb      = (const float*)d_in[6];
  const float* pemb      = (const float*)d_in[7];
  const float* elns      = (const float*)d_in[8];
  const float* elnb      = (const float*)d_in[9];
  const float* Wq = (const float*)d_in[10]; const float* bq = (const float*)d_in[11];
  const float* Wk = (const float*)d_in[12]; const float* bk = (const float*)d_in[13];
  const float* Wv = (const float*)d_in[14]; const float* bv = (const float*)d_in[15];
  const float* Wo = (const float*)d_in[16]; const float* bo = (const float*)d_in[17];
  const float* ln1s = (const float*)d_in[18]; const float* ln1b = (const float*)d_in[19];
  const float* Wff1 = (const float*)d_in[20]; const float* bff1 = (const float*)d_in[21];
  const float* Wff2 = (const float*)d_in[22]; const float* bff2 = (const float*)d_in[23];
  const float* ln2s = (const float*)d_in[24]; const float* ln2b = (const float*)d_in[25];
  const float* d1w = (const float*)d_in[26]; const float* d1b = (const float*)d_in[27];
  const float* d2w = (const float*)d_in[28]; const float* d2b = (const float*)d_in[29];
  const float* hlns = (const float*)d_in[30]; const float* hlnb = (const float*)d_in[31];
  const float* qaw = (const float*)d_in[32]; const float* qab = (const float*)d_in[33];
  float* outf = (float*)d_out;

  // ---- workspace layout (bytes) ----
  char* W = (char*)d_ws;
  u16* wtAll = (u16*)W;
  u16* wtQKV = wtAll;
  u16* wtO   = wtAll + 7077888;
  u16* wtF1  = wtAll + 9437184;
  u16* wtF2  = wtAll + 18874368;
  u16* wtd1  = wtAll + 28311552;
  u16* wtd2  = wtAll + 30670848;
  size_t o = 66060288;
  float* X  = (float*)(W + o);  o += 25165824;
  u16* Xb   = (u16*)(W + o);    o += 12582912;
  u16* Qb   = (u16*)(W + o);    o += 12582912;
  u16* Kb   = (u16*)(W + o);    o += 12582912;
  u16* Vb   = (u16*)(W + o);    o += 12582912;
  u16* T2b  = (u16*)(W + o);    o += 12582912;
  u16* T1b  = Qb;               // alias: FF hidden over dead Q/K/V
  float* R  = (float*)(W + o);  o += 25165824;
  float* Pm = (float*)(W + o);  o += 98304;
  float* Pl = (float*)(W + o);  o += 98304;
  float* Pacc = (float*)(W + o); o += 6291456;
  int* qflag = (int*)(W + o);

  const int Mrows = Bv*Sv;  // 8192
  dim3 tb(32,8);

  k_qdetect<<<1, 256, 0, stream>>>((const unsigned char*)qmask, qflag);
  k_transw<<<dim3(24,24,4), tb, 0, stream>>>(Wq, wtQKV + 0,      Dv, Dv, 589824, 1769472);
  k_transw<<<dim3(24,24,4), tb, 0, stream>>>(Wk, wtQKV + 589824, Dv, Dv, 589824, 1769472);
  k_transw<<<dim3(24,24,4), tb, 0, stream>>>(Wv, wtQKV + 1179648,Dv, Dv, 589824, 1769472);
  k_transw<<<dim3(24,24,4), tb, 0, stream>>>(Wo, wtO,            Dv, Dv, 589824, 589824);
  k_transw<<<dim3(96,24,4), tb, 0, stream>>>(Wff1, wtF1, Dv, FFv, 2359296, 2359296);
  k_transw<<<dim3(24,96,4), tb, 0, stream>>>(Wff2, wtF2, FFv, Dv, 2359296, 2359296);
  k_transw<<<dim3(96,24,1), tb, 0, stream>>>(d1w, wtd1, Dv, FFv, 0, 0);
  k_transw<<<dim3(24,96,1), tb, 0, stream>>>(d2w, wtd2, FFv, Dv, 0, 0);

  k_embed_ln<<<Mrows, 256, 0, stream>>>(input_ids, wemb, pemb, elns, elnb, X, Xb);

  for (int l=0; l<Lv; ++l){
    k_gemm_qkv<<<dim3(6,64,3), 256, 0, stream>>>(Xb, wtQKV + (size_t)l*1769472,
        bq + (size_t)l*Dv, bk + (size_t)l*Dv, bv + (size_t)l*Dv, Qb, Kb, Vb);

    k_attn_sparse<<<dim3(NBv-2, Hv, Bv), 256, 0, stream>>>(Qb, Kb, Vb, amask, rnd, T2b);
    k_attn_global<<<dim3(16, Hv, Bv), 256, 0, stream>>>(Qb, Kb, Vb, amask, Pm, Pl, Pacc);
    k_attn_merge<<<dim3(2, Hv, Bv), 64, 0, stream>>>(Pm, Pl, Pacc, T2b);

    k_gemm<<<dim3(6,64), 256, 0, stream>>>(T2b, wtO + (size_t)l*589824, bo + (size_t)l*Dv, R, nullptr, Dv, Dv, 0);
    k_ln<<<Mrows, 256, 0, stream>>>(X, R, 1, ln1s + (size_t)l*Dv, ln1b + (size_t)l*Dv, X, Xb);

    k_gemm<<<dim3(24,64), 256, 0, stream>>>(Xb, wtF1 + (size_t)l*2359296, bff1 + (size_t)l*FFv, nullptr, T1b, FFv, Dv, 1);
    k_gemm<<<dim3(6,64), 256, 0, stream>>>(T1b, wtF2 + (size_t)l*2359296, bff2 + (size_t)l*Dv, R, nullptr, Dv, FFv, 0);
    k_ln<<<Mrows, 256, 0, stream>>>(X, R, 1, ln2s + (size_t)l*Dv, ln2b + (size_t)l*Dv, X, Xb);
  }

  k_gemm<<<dim3(24,64), 256, 0, stream>>>(Xb, wtd1, d1b, nullptr, T1b, FFv, Dv, 1);
  k_gemm<<<dim3(6,64), 256, 0, stream>>>(T1b, wtd2, d2b, R, nullptr, Dv, FFv, 0);
  k_ln<<<Mrows, 256, 0, stream>>>(R, nullptr, 0, hlns, hlnb, X, nullptr);

  k_logits<<<Mrows, 64, 0, stream>>>(X, qaw, qab, qmask, qflag, outf);
  k_ce<<<1, 256, 0, stream>>>(outf, sp, ep);
}